// Round 4
// baseline (211.021 us; speedup 1.0000x reference)
//
#include <hip/hip_runtime.h>
#include <hip/hip_bf16.h>

// XConv: N=32 P=1024 K=16 DIMS=3 C_IN=64 C_MID=64 C_OUT=128 DM=2; NP=32768
// ws: 32768*256 floats (33.5 MB): holds X2 (untransposed), overwritten in-place by tmp.

#define ELU(x) ((x) > 0.0f ? (x) : (__expf(x) - 1.0f))

__device__ __forceinline__ void lds_fence() {
    asm volatile("s_waitcnt lgkmcnt(0)" ::: "memory");
}

typedef __attribute__((ext_vector_type(8))) short short8v;
typedef __attribute__((ext_vector_type(4))) float f32x4;
#define MFMA32(a, b, c) __builtin_amdgcn_mfma_f32_16x16x32_bf16(a, b, c, 0, 0, 0)

__device__ __forceinline__ short f2bf(float x) {
    __hip_bfloat16 h = __float2bfloat16(x);
    return *reinterpret_cast<short*>(&h);
}
__device__ __forceinline__ float bf2f(short x) {
    unsigned u = ((unsigned)(unsigned short)x) << 16;
    return __uint_as_float(u);
}
__device__ __forceinline__ void gload_lds16(const float* g, float* l) {
    __builtin_amdgcn_global_load_lds(
        (const __attribute__((address_space(1))) void*)g,
        (__attribute__((address_space(3))) void*)l,
        16, 0, 0);
}

// ---------------- Kernel 1: X-transform via MFMA (unchanged from R3) ----------------
#define XW_WC   0        // bf16 frag entries: idx=(part*16+u)*64+lane, 16B each (8192 words)
#define XW_WD1  8192     // wdep1: i*260 + j*16 + k  (4160 words)
#define XW_WD2  12352    // wdep2 same               (4160)
#define XW_BC   16512    // bconv 256
#define XW_BD1  16768    // 256
#define XW_BD2  17024    // 256
#define XW_SCR  17280    // + wave*4368 : per-point stride 273, scr[p*273 + j*17 + s]
#define XW_TOTAL (17280 + 4*4368)   // 34752 words = 139008 B

__global__ __launch_bounds__(256) void k_xform(
    const float* __restrict__ rep, const float* __restrict__ pts,
    const float* __restrict__ wconv, const float* __restrict__ bconv,
    const float* __restrict__ wdep1, const float* __restrict__ bdep1,
    const float* __restrict__ wdep2, const float* __restrict__ bdep2,
    float* __restrict__ x2)
{
    extern __shared__ __align__(16) float sm[];
    short* smh = (short*)sm;
    const int tid = threadIdx.x;

    for (int e = tid; e < 2048; e += 256) {
        const int part = e >> 10, u = (e >> 6) & 15, l = e & 63;
        const int g = l >> 4, s = l & 15;
        const int o = u * 16 + s;
        short8v v;
        if (part == 0) {
            #pragma unroll
            for (int t = 0; t < 8; ++t) v[t] = f2bf(wconv[o*48 + g*8 + t]);
        } else {
            #pragma unroll
            for (int t = 0; t < 4; ++t) v[t] = f2bf(wconv[o*48 + 32 + g*4 + t]);
            #pragma unroll
            for (int t = 4; t < 8; ++t) v[t] = 0;
        }
        *(short8v*)&smh[e * 8] = v;
    }
    for (int e = tid; e < 4096; e += 256) {
        const int i = e >> 8, j = (e >> 4) & 15, k = e & 15;
        sm[XW_WD1 + i*260 + j*16 + k] = wdep1[e];
        sm[XW_WD2 + i*260 + j*16 + k] = wdep2[e];
    }
    sm[XW_BC  + tid] = bconv[tid];
    sm[XW_BD1 + tid] = bdep1[tid];
    sm[XW_BD2 + tid] = bdep2[tid];
    __syncthreads();

    const int wave = tid >> 6, lane = tid & 63;
    const int g = lane >> 4, s = lane & 15;
    const int pt0 = (blockIdx.x * 4 + wave) * 16;

    const int p = pt0 + s;
    const float r0 = rep[p*3], r1 = rep[p*3+1], r2 = rep[p*3+2];
    short8v ah0, al0, ah1, al1;
    #pragma unroll
    for (int e = 0; e < 8; ++e) {
        const int r = g*8 + e;
        const int d = g >> 1, k = r & 15;
        const float v = pts[p*48 + k*3 + d] - (d == 0 ? r0 : r1);
        const short h = f2bf(v);
        ah0[e] = h; al0[e] = f2bf(v - bf2f(h));
    }
    #pragma unroll
    for (int e = 0; e < 4; ++e) {
        const int k = g*4 + e;
        const float v = pts[p*48 + k*3 + 2] - r2;
        const short h = f2bf(v);
        ah1[e] = h; al1[e] = f2bf(v - bf2f(h));
    }
    #pragma unroll
    for (int e = 4; e < 8; ++e) { ah1[e] = 0; al1[e] = 0; }

    f32x4 ex[16];
    #pragma unroll
    for (int u = 0; u < 16; ++u) {
        const float b = sm[XW_BC + u*16 + s];
        f32x4 acc; acc[0] = b; acc[1] = b; acc[2] = b; acc[3] = b;
        const short8v bh0 = *(const short8v*)&smh[(u*64 + lane) * 8];
        const short8v bh1 = *(const short8v*)&smh[((16 + u)*64 + lane) * 8];
        acc = MFMA32(ah0, bh0, acc);
        acc = MFMA32(ah1, bh1, acc);
        acc = MFMA32(al0, bh0, acc);
        acc = MFMA32(al1, bh1, acc);
        f32x4 r;
        r[0] = ELU(acc[0]); r[1] = ELU(acc[1]); r[2] = ELU(acc[2]); r[3] = ELU(acc[3]);
        ex[u] = r;
    }

    const int scrb = XW_SCR + wave * 4368;
    #pragma unroll
    for (int j = 0; j < 16; ++j) {
        const float b = sm[XW_BD1 + s*16 + j];
        f32x4 a; a[0] = b; a[1] = b; a[2] = b; a[3] = b;
        #pragma unroll
        for (int kb = 0; kb < 4; ++kb) {
            const float4 w = *(const float4*)&sm[XW_WD1 + s*260 + j*16 + kb*4];
            a += ex[kb*4+0] * w.x; a += ex[kb*4+1] * w.y;
            a += ex[kb*4+2] * w.z; a += ex[kb*4+3] * w.w;
        }
        #pragma unroll
        for (int q = 0; q < 4; ++q)
            sm[scrb + (g*4+q)*273 + j*17 + s] = ELU(a[q]);
    }
    lds_fence();

    f32x4 xr[16];
    #pragma unroll
    for (int k = 0; k < 16; ++k) {
        f32x4 v;
        #pragma unroll
        for (int q = 0; q < 4; ++q)
            v[q] = sm[scrb + (g*4+q)*273 + s*17 + k];
        xr[k] = v;
    }
    f32x4 oj[16];
    #pragma unroll
    for (int j = 0; j < 16; ++j) {
        const float b = sm[XW_BD2 + s*16 + j];
        f32x4 a; a[0] = b; a[1] = b; a[2] = b; a[3] = b;
        #pragma unroll
        for (int kb = 0; kb < 4; ++kb) {
            const float4 w = *(const float4*)&sm[XW_WD2 + s*260 + j*16 + kb*4];
            a += xr[kb*4+0] * w.x; a += xr[kb*4+1] * w.y;
            a += xr[kb*4+2] * w.z; a += xr[kb*4+3] * w.w;
        }
        oj[j] = a;
    }
    #pragma unroll
    for (int q = 0; q < 4; ++q) {
        const int pp = pt0 + g*4 + q;
        #pragma unroll
        for (int jb = 0; jb < 4; ++jb) {
            *(float4*)&x2[pp*256 + s*16 + jb*4] =
                make_float4(oj[jb*4+0][q], oj[jb*4+1][q], oj[jb*4+2][q], oj[jb*4+3][q]);
        }
    }
}

// ---------------- Kernel 2: MFMA features, LDS-staged fts, <=128 regs ----------------
// Per wave: 8 points. fts tile (4KB) DMA'd to per-wave LDS with source-side chunk swizzle
// f(t) = t ^ ((t>>6)&3) ^ (((t>>6)&1)<<2)  (involution; bank-spreads the strided b32 reads).
__device__ __forceinline__ void stage_fts(const float* __restrict__ fts, int pt,
                                          float* sf, int lane) {
    const float* src = fts + (size_t)pt * 1024;
    gload_lds16(src + 4*(0*64 + (lane ^ 0)), sf + 0*256);
    gload_lds16(src + 4*(1*64 + (lane ^ 5)), sf + 1*256);
    gload_lds16(src + 4*(2*64 + (lane ^ 2)), sf + 2*256);
    gload_lds16(src + 4*(3*64 + (lane ^ 7)), sf + 3*256);
}

__global__ __launch_bounds__(256, 4) void k_feat(
    const float* __restrict__ rep, const float* __restrict__ pts, const float* __restrict__ fts,
    const float* __restrict__ w1, const float* __restrict__ b1,
    const float* __restrict__ w2, const float* __restrict__ b2,
    const float* __restrict__ wdw, const float* __restrict__ bdw,
    float* __restrict__ xbuf)
{
    __shared__ unsigned swdwp[2048];            // wdw bf16-pairs: [m][c][w ^ ((c&3)<<1)]
    __shared__ float sbdw[256];
    __shared__ __align__(16) float sfts[4096];  // 4 waves x 1KB-point tile (chunk-swizzled)
    const int tid = threadIdx.x;
    for (int e = tid; e < 2048; e += 256) {
        const int m = e >> 10, c = (e >> 3) & 127, w = e & 7;
        const unsigned lo = (unsigned)(unsigned short)f2bf(wdw[c*32 + m*16 + 2*w]);
        const unsigned hi = (unsigned)(unsigned short)f2bf(wdw[c*32 + m*16 + 2*w + 1]);
        swdwp[m*1024 + c*8 + (w ^ ((c & 3) << 1))] = lo | (hi << 16);
    }
    sbdw[tid] = bdw[tid];
    __syncthreads();

    const int lane = tid & 63, wave = tid >> 6;
    const int g = lane >> 4, s = lane & 15;

    // one-time per-lane constants
    short8v w2f[4][2];
    #pragma unroll
    for (int nt = 0; nt < 4; ++nt)
        #pragma unroll
        for (int h = 0; h < 2; ++h) {
            short8v f;
            #pragma unroll
            for (int e = 0; e < 8; ++e)
                f[e] = f2bf(w2[(h*32 + g*8 + e)*64 + nt*16 + s]);
            w2f[nt][h] = f;
        }
    unsigned w1pa[16], w1pb[16];
    #pragma unroll
    for (int t = 0; t < 2; ++t)
        #pragma unroll
        for (int e = 0; e < 8; ++e) {
            const int j = t*32 + g*8 + e, idx = t*8 + e;
            w1pa[idx] = (unsigned)(unsigned short)f2bf(w1[j])
                      | (((unsigned)(unsigned short)f2bf(w1[64 + j])) << 16);
            w1pb[idx] = (unsigned)(unsigned short)f2bf(w1[128 + j])
                      | (((unsigned)(unsigned short)f2bf(b1[j])) << 16);
        }
    float b2c[4];
    #pragma unroll
    for (int nt = 0; nt < 4; ++nt) b2c[nt] = b2[nt*16 + s];

    const int pt0 = (blockIdx.x * 4 + wave) * 8;
    float* sf = &sfts[wave * 1024];
    // fts read bases (float index into sfts, swizzle folded in)
    const int aE = wave*1024 + 256*g + 4*((s >> 2) ^ g) + (s & 3) + 16*(g & 1);
    const int aO = aE + 16 - 32*(g & 1);

    // prologue: stage pt0
    stage_fts(fts, pt0, sf, lane);
    float4 pf_x = *(const float4*)&xbuf[(size_t)pt0*256 + s*16 + g*4];
    float pf_p0 = pts[pt0*48 + s*3 + 0] - rep[pt0*3 + 0];
    float pf_p1 = pts[pt0*48 + s*3 + 1] - rep[pt0*3 + 1];
    float pf_p2 = pts[pt0*48 + s*3 + 2] - rep[pt0*3 + 2];

    for (int it = 0; it < 8; ++it) {
        const int pt = pt0 + it;
        const float p0 = pf_p0, p1 = pf_p1, p2 = pf_p2;
        const float4 xv = pf_x;

        // ---- phase A: h1 (bf16 w1) in A-frag layout; h2 via 8 MFMA ----
        short8v af0, af1;
        #pragma unroll
        for (int t = 0; t < 2; ++t) {
            short8v f;
            #pragma unroll
            for (int e = 0; e < 8; ++e) {
                const int idx = t*8 + e;
                const unsigned pa = w1pa[idx], pb = w1pb[idx];
                const float wx = __uint_as_float(pa << 16);
                const float wy = __uint_as_float(pa & 0xffff0000u);
                const float wz = __uint_as_float(pb << 16);
                const float bb = __uint_as_float(pb & 0xffff0000u);
                float h = bb + p0*wx + p1*wy + p2*wz;
                h = ELU(h);
                f[e] = f2bf(h);
            }
            if (t == 0) af0 = f; else af1 = f;
        }
        f32x4 hacc[4];
        #pragma unroll
        for (int nt = 0; nt < 4; ++nt) {
            f32x4 a; a[0] = b2c[nt]; a[1] = b2c[nt]; a[2] = b2c[nt]; a[3] = b2c[nt];
            a = MFMA32(af0, w2f[nt][0], a);
            a = MFMA32(af1, w2f[nt][1], a);
            hacc[nt] = a;
        }
        short8v a2 = (short8v)0;
        a2[0] = f2bf(xv.x); a2[1] = f2bf(xv.y);
        a2[2] = f2bf(xv.z); a2[3] = f2bf(xv.w);

        // ---- read fts frags from LDS (DMA for pt complete: fence) ----
        asm volatile("s_waitcnt vmcnt(0)" ::: "memory");
        float fr[4][4];
        #pragma unroll
        for (int up = 0; up < 4; ++up)
            #pragma unroll
            for (int e = 0; e < 4; ++e)
                fr[up][e] = sfts[((up & 1) ? aO : aE) + 64*e + 32*(up >> 1)];
        asm volatile("s_waitcnt lgkmcnt(0)" ::: "memory");

        // ---- stage next point (overlaps phase B/C) ----
        if (it < 7) {
            stage_fts(fts, pt + 1, sf, lane);
            pf_x = *(const float4*)&xbuf[(size_t)(pt+1)*256 + s*16 + g*4];
            pf_p0 = pts[(pt+1)*48 + s*3 + 0] - rep[(pt+1)*3 + 0];
            pf_p1 = pts[(pt+1)*48 + s*3 + 1] - rep[(pt+1)*3 + 1];
            pf_p2 = pts[(pt+1)*48 + s*3 + 2] - rep[(pt+1)*3 + 2];
        }

        // ---- phase B+C fused per 16-col tile u ----
        #pragma unroll
        for (int u = 0; u < 8; ++u) {
            short8v bfrag = (short8v)0;
            if (u < 4) {
                #pragma unroll
                for (int q = 0; q < 4; ++q) bfrag[q] = f2bf(ELU(hacc[u][q]));
            } else {
                #pragma unroll
                for (int e = 0; e < 4; ++e) bfrag[e] = f2bf(fr[u-4][e]);
            }
            f32x4 z; z[0] = 0.f; z[1] = 0.f; z[2] = 0.f; z[3] = 0.f;
            const f32x4 fx = MFMA32(a2, bfrag, z);   // fts_X[4g+q][u*16+s]

            const int c = u*16 + s;
            const int wo = c*8 + ((2*g) ^ ((s & 3) << 1));
            const uint2 wm0 = *(const uint2*)&swdwp[wo];
            const uint2 wm1 = *(const uint2*)&swdwp[1024 + wo];
            const float a0 = __uint_as_float(wm0.x << 16);
            const float a1 = __uint_as_float(wm0.x & 0xffff0000u);
            const float a2f = __uint_as_float(wm0.y << 16);
            const float a3 = __uint_as_float(wm0.y & 0xffff0000u);
            const float c0 = __uint_as_float(wm1.x << 16);
            const float c1 = __uint_as_float(wm1.x & 0xffff0000u);
            const float c2 = __uint_as_float(wm1.y << 16);
            const float c3 = __uint_as_float(wm1.y & 0xffff0000u);
            float q0 = fx[0]*a0 + fx[1]*a1 + fx[2]*a2f + fx[3]*a3;
            float q1 = fx[0]*c0 + fx[1]*c1 + fx[2]*c2 + fx[3]*c3;
            q0 += __shfl_xor(q0, 16); q0 += __shfl_xor(q0, 32);
            q1 += __shfl_xor(q1, 16); q1 += __shfl_xor(q1, 32);
            if (lane < 16) {
                float2 r; r.x = q0 + sbdw[2*c]; r.y = q1 + sbdw[2*c + 1];
                *(float2*)&xbuf[(size_t)pt*256 + 2*c] = r;
            }
        }
    }
}

// ---------------- Kernel 3: out = elu(tmp @ wpw^T + bpw) via MFMA ----------------
// Block: 256 thr / 4 waves; wave = 16 rows, 128 cols, K=256. wpw bf16 in LDS (swizzled),
// tmp as hi/lo bf16 split (fp32-accurate on the data operand).
__global__ __launch_bounds__(256) void k_out(
    const float* __restrict__ tmp, const float* __restrict__ wpw,
    const float* __restrict__ bpw, float* __restrict__ out)
{
    __shared__ unsigned sb[16384];   // 64KB: [n][chunk cb^(n&7)][wi]
    const int tid = threadIdx.x;
    for (int e = tid; e < 16384; e += 256) {
        const int n = e >> 7, kw = e & 127;
        const int cb = kw >> 2, wi = kw & 3;
        const unsigned lo = (unsigned)(unsigned short)f2bf(wpw[n*256 + 2*kw]);
        const unsigned hi = (unsigned)(unsigned short)f2bf(wpw[n*256 + 2*kw + 1]);
        sb[n*128 + ((cb ^ (n & 7)) << 2) + wi] = lo | (hi << 16);
    }
    __syncthreads();

    const int lane = tid & 63, wave = tid >> 6;
    const int g = lane >> 4, s = lane & 15;
    const int row = blockIdx.x * 64 + wave * 16 + s;

    f32x4 acc[8];
    #pragma unroll
    for (int nt = 0; nt < 8; ++nt) {
        const float b = bpw[nt*16 + s];
        acc[nt][0] = b; acc[nt][1] = b; acc[nt][2] = b; acc[nt][3] = b;
    }

    const float* arow = tmp + (size_t)row * 256 + g*8;
    float4 pa0 = *(const float4*)(arow);
    float4 pa1 = *(const float4*)(arow + 4);

    #pragma unroll
    for (int kk = 0; kk < 8; ++kk) {
        const float4 a0 = pa0, a1 = pa1;
        if (kk < 7) {
            pa0 = *(const float4*)(arow + (kk+1)*32);
            pa1 = *(const float4*)(arow + (kk+1)*32 + 4);
        }
        short8v ah, al;
        const float av[8] = {a0.x, a0.y, a0.z, a0.w, a1.x, a1.y, a1.z, a1.w};
        #pragma unroll
        for (int e = 0; e < 8; ++e) {
            const short h = f2bf(av[e]);
            ah[e] = h;
            al[e] = f2bf(av[e] - bf2f(h));
        }
        #pragma unroll
        for (int nt = 0; nt < 8; ++nt) {
            const short8v bf = *(const short8v*)&sb[(nt*16 + s)*128 + (((kk*4 + g) ^ (s & 7)) << 2)];
            acc[nt] = MFMA32(ah, bf, acc[nt]);
            acc[nt] = MFMA32(al, bf, acc[nt]);
        }
    }
    const int rbase = blockIdx.x * 64 + wave * 16 + 4*g;
    #pragma unroll
    for (int nt = 0; nt < 8; ++nt)
        #pragma unroll
        for (int q = 0; q < 4; ++q)
            out[(size_t)(rbase + q) * 128 + nt*16 + s] = ELU(acc[nt][q]);
}

extern "C" void kernel_launch(void* const* d_in, const int* in_sizes, int n_in,
                              void* d_out, int out_size, void* d_ws, size_t ws_size,
                              hipStream_t stream)
{
    (void)in_sizes; (void)n_in; (void)out_size; (void)ws_size;
    const float* rep   = (const float*)d_in[0];
    const float* pts   = (const float*)d_in[1];
    const float* fts   = (const float*)d_in[2];
    const float* w1    = (const float*)d_in[3];
    const float* b1    = (const float*)d_in[4];
    const float* w2    = (const float*)d_in[5];
    const float* b2    = (const float*)d_in[6];
    const float* wconv = (const float*)d_in[7];
    const float* bconv = (const float*)d_in[8];
    const float* wdep1 = (const float*)d_in[9];
    const float* bdep1 = (const float*)d_in[10];
    const float* wdep2 = (const float*)d_in[11];
    const float* bdep2 = (const float*)d_in[12];
    const float* wdw   = (const float*)d_in[13];
    const float* bdw   = (const float*)d_in[14];
    const float* wpw   = (const float*)d_in[15];
    const float* bpw   = (const float*)d_in[16];
    float* out  = (float*)d_out;
    float* xbuf = (float*)d_ws;   // 32768*256 floats = 33.5 MB

    hipFuncSetAttribute((const void*)k_xform, hipFuncAttributeMaxDynamicSharedMemorySize, XW_TOTAL*4);

    k_xform<<<dim3(512),  dim3(256), XW_TOTAL*4, stream>>>(rep, pts, wconv, bconv, wdep1, bdep1, wdep2, bdep2, xbuf);
    k_feat <<<dim3(1024), dim3(256), 0, stream>>>(rep, pts, fts, w1, b1, w2, b2, wdw, bdw, xbuf);
    k_out  <<<dim3(512),  dim3(256), 0, stream>>>(xbuf, wpw, bpw, out);
}